// Round 13
// baseline (442.274 us; speedup 1.0000x reference)
//
#include <hip/hip_runtime.h>

// CombinedLoss: 0.7*MSE + 0.3*mean_b softDTW_gamma.  B=64, T=1024, C=8, fp32.
// R20: 2 rows/lane -> TWO independent softmin chains per step.
// R18/R19 proved the single chain's latency cannot be overlapped by source
// placement (compiler converges to ~275cy/diag regardless).  Now each lane
// computes cells (128G+l, .) and (128G+64+l, .) per diag: independent chains
// that the scheduler must interleave.  Bottom-half halo row 128G+63 = lane
// 63's top r1, via v_readlane before the top update.  dg=up_prev carry per
// half (R19, exact).  8 waves x 128 rows per batch: 128 blocks x 256 thr,
// 1 cross-block boundary (row 512) with the proven self-validating 8B
// atomics (kb=384, RING=1152); intra-block halos via s_row + progress flags.
// 48B-stride padded column layout (bank floor).  Hot windows u in [8,62]
// (both halves unmasked); D(u+1) prefetched depth-1 during window u.
// ws: [0,128) mse | [256,320) sdtw | u64 rings @ float-offset 320 (~590 KB).

constexpr int TT = 1024;
constexpr float ALPHA_ = 0.7f;
constexpr float FINF = 1000000000.0f;
constexpr int RING = 1152;

__device__ __forceinline__ float shflup1(float old0, float v) {
    return __int_as_float(__builtin_amdgcn_update_dpp(
        __float_as_int(old0), __float_as_int(v), 0x138, 0xf, 0xf, false));
}
__device__ __forceinline__ float rotdn1(float v) {
    return __int_as_float(__builtin_amdgcn_update_dpp(
        0, __float_as_int(v), 0x130, 0xf, 0xf, false));
}

__global__ __launch_bounds__(256) void sdtw_band_kernel(
    const float* __restrict__ pred, const float* __restrict__ target,
    float* __restrict__ ws)
{
    // col j: A-half at 3j, B-half at 3j+1, y2 at 3j+2.x (48B stride)
    __shared__ float4 s_c4[TT * 3];
    __shared__ float  s_row[4][RING];    // per-wave bottom row (local diag idx)
    __shared__ float  s_red[4];
    __shared__ int    s_prog[4];         // last completed LOCAL window per wave

    const int blk = blockIdx.x;
    const int b   = blk & 63;                  // batch (h*64+b: same-XCD pair)
    const int h   = blk >> 6;                  // half: rows [512h, 512h+511]
    const int tid = threadIdx.x;
    const int l   = tid & 63;
    const int w_  = __builtin_amdgcn_readfirstlane(tid >> 6);
    const int G   = (h << 2) + w_;             // global wave 0..7
    const int gbase = G << 7;                  // 128G
    const int rowt  = gbase + l;
    const int rowb  = gbase + 64 + l;

    if (tid < 4) s_prog[tid] = -1;

    const float* prt = pred   + ((size_t)b * TT + rowt) * 8;
    const float* trt = target + ((size_t)b * TT + rowt) * 8;
    const float* prb = pred   + ((size_t)b * TT + rowb) * 8;
    const float* trb = target + ((size_t)b * TT + rowb) * 8;
    const float4 pat = ((const float4*)prt)[0];
    const float4 pbt = ((const float4*)prt)[1];
    const float4 pab = ((const float4*)prb)[0];
    const float4 pbb = ((const float4*)prb)[1];
    const float4 qat = ((const float4*)trt)[0];
    const float4 qbt = ((const float4*)trt)[1];
    const float4 qab = ((const float4*)trb)[0];
    const float4 qbb = ((const float4*)trb)[1];

    float x2t = 0.f, x2b = 0.f, msep = 0.f;
    {
        const float pt[8] = {pat.x,pat.y,pat.z,pat.w,pbt.x,pbt.y,pbt.z,pbt.w};
        const float tt[8] = {qat.x,qat.y,qat.z,qat.w,qbt.x,qbt.y,qbt.z,qbt.w};
        const float pb_[8]= {pab.x,pab.y,pab.z,pab.w,pbb.x,pbb.y,pbb.z,pbb.w};
        const float tb_[8]= {qab.x,qab.y,qab.z,qab.w,qbb.x,qbb.y,qbb.z,qbb.w};
        #pragma unroll
        for (int c = 0; c < 8; ++c) {
            x2t = fmaf(pt[c],  pt[c],  x2t);
            x2b = fmaf(pb_[c], pb_[c], x2b);
            float d1 = pt[c]  - tt[c];
            float d2 = pb_[c] - tb_[c];
            msep = fmaf(d1, d1, msep);
            msep = fmaf(d2, d2, msep);
        }
    }
    // stage all 1024 columns (4 per thread), padded layout
    const float* tg = target + (size_t)b * TT * 8;
    #pragma unroll
    for (int c0 = 0; c0 < 4; ++c0) {
        const int col = tid + (c0 << 8);
        const float4 u0 = ((const float4*)(tg + (size_t)col * 8))[0];
        const float4 u1 = ((const float4*)(tg + (size_t)col * 8))[1];
        const float y2 = u0.x*u0.x + u0.y*u0.y + u0.z*u0.z + u0.w*u0.w
                       + u1.x*u1.x + u1.y*u1.y + u1.z*u1.z + u1.w*u1.w;
        s_c4[3*col]   = make_float4(-2.f*u0.x, -2.f*u0.y, -2.f*u0.z, -2.f*u0.w);
        s_c4[3*col+1] = make_float4(-2.f*u1.x, -2.f*u1.y, -2.f*u1.z, -2.f*u1.w);
        s_c4[3*col+2] = make_float4(y2, 0.f, 0.f, 0.f);
    }
    #pragma unroll
    for (int off = 32; off > 0; off >>= 1) msep += __shfl_down(msep, off, 64);
    if (l == 0) s_red[w_] = msep;
    __syncthreads();                      // the ONLY block-wide barrier
    if (tid == 0) ws[blk] = s_red[0] + s_red[1] + s_red[2] + s_red[3];

    unsigned long long* rings = (unsigned long long*)(ws + 320);
    unsigned long long* pub = rings + (size_t)b * RING;   // h==0 && w_==3
    unsigned long long* con = rings + (size_t)b * RING;   // h==1 && w_==0
    const int KB = 384;                   // abs diag of publisher local 0
    const int KMAX = KB + RING - 1;       // 1535

    const float c1 = 7.213475204444817f;     // log2(e)/gamma
    const float c2 = 0.13862943611198906f;   // gamma*ln(2)

    float r1t = FINF, r1b = FINF;
    float dgpt, dgpb = FINF;
    unsigned long long pe1 = 0;
    int ppf = 0;
    float hpf1 = 0.f;
    int hpff = 0;
    float hv;

    // ---- seed dgpt (needs halo diag gbase*?-2 = k0(0)-2, lane 0 only) ----
    {
        float hvd0;
        if (w_ == 0) {
            if (h == 0) {
                hvd0 = (l == 0) ? 0.0f : FINF;   // R[-1][-1]=0 for (0,0)
            } else {
                const int kk2 = 510 + l;          // k0(0)-2+l, k0=512
                const int id2 = min(kk2 - KB, RING - 1);
                const bool n2 = (l < 16);
                unsigned long long e2;
                do {
                    e2 = __hip_atomic_load(con + id2, __ATOMIC_RELAXED,
                                           __HIP_MEMORY_SCOPE_AGENT);
                } while (!__all((!n2) | ((int)(e2 >> 32) == kk2)));
                hvd0 = n2 ? __uint_as_float((unsigned)e2) : FINF;
            }
        } else {
            int pv;
            do {
                pv = __hip_atomic_load(&s_prog[w_ - 1], __ATOMIC_ACQUIRE,
                                       __HIP_MEMORY_SCOPE_WORKGROUP);
            } while (pv < 7);                     // covers local diag 126
            hvd0 = s_row[w_ - 1][min(126 + l, RING - 1)];
        }
        dgpt = shflup1(hvd0, FINF);               // lane0 <- hvd0[0]
    }

// ---- paired chain step: both halves, independent chains ----
#define CHAIN2(i, DINT, DINB, RHB, MASKED) do {                             \
        const float t63_ = __int_as_float(                                  \
            __builtin_amdgcn_readlane(__float_as_int(r1t), 63));            \
        const float upt_ = shflup1(hv, r1t);                                \
        hv = rotdn1(hv);                                                    \
        const float upb_ = shflup1(t63_, r1b);                              \
        float mt_, Mt_, mb_, Mb_;                                           \
        asm("v_min3_f32 %0,%1,%2,%3"                                        \
            : "=v"(mt_) : "v"(upt_), "v"(r1t), "v"(dgpt));                  \
        asm("v_max3_f32 %0,%1,%2,%3"                                        \
            : "=v"(Mt_) : "v"(upt_), "v"(r1t), "v"(dgpt));                  \
        const float mdt_ = __builtin_amdgcn_fmed3f(upt_, r1t, dgpt);        \
        asm("v_min3_f32 %0,%1,%2,%3"                                        \
            : "=v"(mb_) : "v"(upb_), "v"(r1b), "v"(dgpb));                  \
        asm("v_max3_f32 %0,%1,%2,%3"                                        \
            : "=v"(Mb_) : "v"(upb_), "v"(r1b), "v"(dgpb));                  \
        const float mdb_ = __builtin_amdgcn_fmed3f(upb_, r1b, dgpb);        \
        dgpt = upt_; dgpb = upb_;                                           \
        const float mct_ = mt_ * c1, mcb_ = mb_ * c1;                       \
        const float eat_ = __builtin_amdgcn_exp2f(fmaf(mdt_, -c1, mct_));   \
        const float ebt_ = __builtin_amdgcn_exp2f(fmaf(Mt_,  -c1, mct_));   \
        const float eab_ = __builtin_amdgcn_exp2f(fmaf(mdb_, -c1, mcb_));   \
        const float ebb_ = __builtin_amdgcn_exp2f(fmaf(Mb_,  -c1, mcb_));   \
        const float lgt_ = __builtin_amdgcn_logf(1.0f + (eat_ + ebt_));     \
        const float lgb_ = __builtin_amdgcn_logf(1.0f + (eab_ + ebb_));     \
        float rnt_ = (DINT) + fmaf(-c2, lgt_, mt_);                         \
        float rnb_ = (DINB) + fmaf(-c2, lgb_, mb_);                         \
        if (MASKED) {                                                       \
            rnt_ = ((unsigned)(jb0t + (i))      < (unsigned)TT) ? rnt_ : FINF; \
            rnb_ = ((unsigned)(jb0t + (i) - 64) < (unsigned)TT) ? rnb_ : FINF; \
        }                                                                   \
        r1t = rnt_; r1b = rnb_; RHB = rnb_;                                 \
    } while (0)

// ---- hot loads: both halves' columns for diag i of window u+1 ----
#define LOADH(i, AT,BT,YT, AB,BB,YB) do {                                   \
        const int jt_ = jb1t + (i);                                         \
        const int jb_ = jt_ - 64;                                           \
        AT = s_c4[3*jt_]; BT = s_c4[3*jt_+1]; YT = s_c4[3*jt_+2].x;         \
        AB = s_c4[3*jb_]; BB = s_c4[3*jb_+1]; YB = s_c4[3*jb_+2].x;         \
    } while (0)

// ---- D math for a loaded buffer pair ----
#define DM2(AT,BT,YT, AB,BB,YB, DT, DB) do {                                \
        float a1_ = x2t + YT, a2_ = 0.f, a3_ = x2b + YB, a4_ = 0.f;         \
        a1_ = fmaf(pat.x, AT.x, a1_);  a2_ = fmaf(pat.y, AT.y, a2_);        \
        a1_ = fmaf(pat.z, AT.z, a1_);  a2_ = fmaf(pat.w, AT.w, a2_);        \
        a1_ = fmaf(pbt.x, BT.x, a1_);  a2_ = fmaf(pbt.y, BT.y, a2_);        \
        a1_ = fmaf(pbt.z, BT.z, a1_);  a2_ = fmaf(pbt.w, BT.w, a2_);        \
        a3_ = fmaf(pab.x, AB.x, a3_);  a4_ = fmaf(pab.y, AB.y, a4_);        \
        a3_ = fmaf(pab.z, AB.z, a3_);  a4_ = fmaf(pab.w, AB.w, a4_);        \
        a3_ = fmaf(pbb.x, BB.x, a3_);  a4_ = fmaf(pbb.y, BB.y, a4_);        \
        a3_ = fmaf(pbb.z, BB.z, a3_);  a4_ = fmaf(pbb.w, BB.w, a4_);        \
        DT = a1_ + a2_; DB = a3_ + a4_;                                     \
    } while (0)

// ---- clamped D, both halves (edge windows / prologue) ----
#define DCL2(JB, i, DT, DB) do {                                            \
        int jt_ = (JB) + (i);                                               \
        int jb_ = jt_ - 64;                                                 \
        jt_ = jt_ < 0 ? 0 : (jt_ > (TT-1) ? (TT-1) : jt_);                  \
        jb_ = jb_ < 0 ? 0 : (jb_ > (TT-1) ? (TT-1) : jb_);                  \
        const float4 at_ = s_c4[3*jt_]; const float4 bt_ = s_c4[3*jt_+1];   \
        const float  yt_ = s_c4[3*jt_+2].x;                                 \
        const float4 ab_ = s_c4[3*jb_]; const float4 bb_ = s_c4[3*jb_+1];   \
        const float  yb_ = s_c4[3*jb_+2].x;                                 \
        DM2(at_,bt_,yt_, ab_,bb_,yb_, DT, DB);                              \
    } while (0)

    // D for window 0 (prologue, clamped)
    float Dct0,Dct1,Dct2,Dct3,Dct4,Dct5,Dct6,Dct7;
    float Dct8,Dct9,Dct10,Dct11,Dct12,Dct13,Dct14,Dct15;
    float Dcb0,Dcb1,Dcb2,Dcb3,Dcb4,Dcb5,Dcb6,Dcb7;
    float Dcb8,Dcb9,Dcb10,Dcb11,Dcb12,Dcb13,Dcb14,Dcb15;
    {
        const int jb = -l;
        DCL2(jb, 0,Dct0 ,Dcb0 ); DCL2(jb, 1,Dct1 ,Dcb1 );
        DCL2(jb, 2,Dct2 ,Dcb2 ); DCL2(jb, 3,Dct3 ,Dcb3 );
        DCL2(jb, 4,Dct4 ,Dcb4 ); DCL2(jb, 5,Dct5 ,Dcb5 );
        DCL2(jb, 6,Dct6 ,Dcb6 ); DCL2(jb, 7,Dct7 ,Dcb7 );
        DCL2(jb, 8,Dct8 ,Dcb8 ); DCL2(jb, 9,Dct9 ,Dcb9 );
        DCL2(jb,10,Dct10,Dcb10); DCL2(jb,11,Dct11,Dcb11);
        DCL2(jb,12,Dct12,Dcb12); DCL2(jb,13,Dct13,Dcb13);
        DCL2(jb,14,Dct14,Dcb14); DCL2(jb,15,Dct15,Dcb15);
    }
    float rhb14_last = FINF;
    float4 At0,Bt0,At1,Bt1, Ab0,Bb0,Ab1,Bb1;
    float  Yt0,Yt1, Yb0,Yb1;

    for (int u = 0; u <= 71; ++u) {
        const int k0 = gbase + (u << 4);
        const int jb0t = (u << 4) - l;       // top col of diag k0 at this lane
        const int jb1t = jb0t + 16;

        // ---- stage halo hv (diag k0-1), lane0-consumed ----
        if (w_ == 0) {
            if (h == 0) {
                hv = FINF;
            } else {
                const int kk1 = k0 - 1 + l;
                const int id1 = min(kk1 - KB, RING - 1);
                const bool n1 = (l < 16) && (kk1 <= KMAX);
                unsigned long long e1;
                if (ppf) { e1 = pe1; ppf = 0; }
                else {
                    e1 = __hip_atomic_load(con + id1, __ATOMIC_RELAXED,
                                           __HIP_MEMORY_SCOPE_AGENT);
                }
                while (!__all((!n1) | ((int)(e1 >> 32) == kk1))) {
                    e1 = __hip_atomic_load(con + id1, __ATOMIC_RELAXED,
                                           __HIP_MEMORY_SCOPE_AGENT);
                }
                hv = n1 ? __uint_as_float((unsigned)e1) : FINF;
            }
        } else {
            if (hpff) { hv = hpf1; hpff = 0; }
            else {
                const int need = (u + 8 < 71) ? (u + 8) : 71;
                int pv;
                do {
                    pv = __hip_atomic_load(&s_prog[w_ - 1], __ATOMIC_ACQUIRE,
                                           __HIP_MEMORY_SCOPE_WORKGROUP);
                } while (pv < need);
                hv = s_row[w_ - 1][min((u << 4) + 127 + l, RING - 1)];
            }
        }

        float rhb0,rhb1,rhb2,rhb3,rhb4,rhb5,rhb6,rhb7;
        float rhb8,rhb9,rhb10,rhb11,rhb12,rhb13,rhb14,rhb15;

        if (u >= 8 && u <= 62) {
            // hot: unmasked chains + depth-1 pipelined D(u+1)
            LOADH( 0, At0,Bt0,Yt0, Ab0,Bb0,Yb0);
            CHAIN2( 0, Dct0 , Dcb0 , rhb0 , 0);
            LOADH( 1, At1,Bt1,Yt1, Ab1,Bb1,Yb1);
            DM2(At0,Bt0,Yt0, Ab0,Bb0,Yb0, Dct0 , Dcb0 );
            CHAIN2( 1, Dct1 , Dcb1 , rhb1 , 0);
            LOADH( 2, At0,Bt0,Yt0, Ab0,Bb0,Yb0);
            DM2(At1,Bt1,Yt1, Ab1,Bb1,Yb1, Dct1 , Dcb1 );
            CHAIN2( 2, Dct2 , Dcb2 , rhb2 , 0);
            LOADH( 3, At1,Bt1,Yt1, Ab1,Bb1,Yb1);
            DM2(At0,Bt0,Yt0, Ab0,Bb0,Yb0, Dct2 , Dcb2 );
            CHAIN2( 3, Dct3 , Dcb3 , rhb3 , 0);
            LOADH( 4, At0,Bt0,Yt0, Ab0,Bb0,Yb0);
            DM2(At1,Bt1,Yt1, Ab1,Bb1,Yb1, Dct3 , Dcb3 );
            CHAIN2( 4, Dct4 , Dcb4 , rhb4 , 0);
            LOADH( 5, At1,Bt1,Yt1, Ab1,Bb1,Yb1);
            DM2(At0,Bt0,Yt0, Ab0,Bb0,Yb0, Dct4 , Dcb4 );
            CHAIN2( 5, Dct5 , Dcb5 , rhb5 , 0);
            LOADH( 6, At0,Bt0,Yt0, Ab0,Bb0,Yb0);
            DM2(At1,Bt1,Yt1, Ab1,Bb1,Yb1, Dct5 , Dcb5 );
            CHAIN2( 6, Dct6 , Dcb6 , rhb6 , 0);
            LOADH( 7, At1,Bt1,Yt1, Ab1,Bb1,Yb1);
            DM2(At0,Bt0,Yt0, Ab0,Bb0,Yb0, Dct6 , Dcb6 );
            CHAIN2( 7, Dct7 , Dcb7 , rhb7 , 0);
            LOADH( 8, At0,Bt0,Yt0, Ab0,Bb0,Yb0);
            DM2(At1,Bt1,Yt1, Ab1,Bb1,Yb1, Dct7 , Dcb7 );
            CHAIN2( 8, Dct8 , Dcb8 , rhb8 , 0);
            LOADH( 9, At1,Bt1,Yt1, Ab1,Bb1,Yb1);
            DM2(At0,Bt0,Yt0, Ab0,Bb0,Yb0, Dct8 , Dcb8 );
            CHAIN2( 9, Dct9 , Dcb9 , rhb9 , 0);
            LOADH(10, At0,Bt0,Yt0, Ab0,Bb0,Yb0);
            DM2(At1,Bt1,Yt1, Ab1,Bb1,Yb1, Dct9 , Dcb9 );
            CHAIN2(10, Dct10, Dcb10, rhb10, 0);
            LOADH(11, At1,Bt1,Yt1, Ab1,Bb1,Yb1);
            DM2(At0,Bt0,Yt0, Ab0,Bb0,Yb0, Dct10, Dcb10);
            CHAIN2(11, Dct11, Dcb11, rhb11, 0);
            LOADH(12, At0,Bt0,Yt0, Ab0,Bb0,Yb0);
            DM2(At1,Bt1,Yt1, Ab1,Bb1,Yb1, Dct11, Dcb11);
            CHAIN2(12, Dct12, Dcb12, rhb12, 0);
            LOADH(13, At1,Bt1,Yt1, Ab1,Bb1,Yb1);
            DM2(At0,Bt0,Yt0, Ab0,Bb0,Yb0, Dct12, Dcb12);
            CHAIN2(13, Dct13, Dcb13, rhb13, 0);
            LOADH(14, At0,Bt0,Yt0, Ab0,Bb0,Yb0);
            DM2(At1,Bt1,Yt1, Ab1,Bb1,Yb1, Dct13, Dcb13);
            CHAIN2(14, Dct14, Dcb14, rhb14, 0);
            LOADH(15, At1,Bt1,Yt1, Ab1,Bb1,Yb1);
            DM2(At0,Bt0,Yt0, Ab0,Bb0,Yb0, Dct14, Dcb14);
            CHAIN2(15, Dct15, Dcb15, rhb15, 0);
            DM2(At1,Bt1,Yt1, Ab1,Bb1,Yb1, Dct15, Dcb15);
        } else {
            // edge: masked chains; clamped D for u+1 (skip at u=71)
            CHAIN2( 0,Dct0 ,Dcb0 ,rhb0 ,1); CHAIN2( 1,Dct1 ,Dcb1 ,rhb1 ,1);
            CHAIN2( 2,Dct2 ,Dcb2 ,rhb2 ,1); CHAIN2( 3,Dct3 ,Dcb3 ,rhb3 ,1);
            CHAIN2( 4,Dct4 ,Dcb4 ,rhb4 ,1); CHAIN2( 5,Dct5 ,Dcb5 ,rhb5 ,1);
            CHAIN2( 6,Dct6 ,Dcb6 ,rhb6 ,1); CHAIN2( 7,Dct7 ,Dcb7 ,rhb7 ,1);
            CHAIN2( 8,Dct8 ,Dcb8 ,rhb8 ,1); CHAIN2( 9,Dct9 ,Dcb9 ,rhb9 ,1);
            CHAIN2(10,Dct10,Dcb10,rhb10,1); CHAIN2(11,Dct11,Dcb11,rhb11,1);
            CHAIN2(12,Dct12,Dcb12,rhb12,1); CHAIN2(13,Dct13,Dcb13,rhb13,1);
            CHAIN2(14,Dct14,Dcb14,rhb14,1); CHAIN2(15,Dct15,Dcb15,rhb15,1);
            if (u < 71) {
                DCL2(jb1t, 0,Dct0 ,Dcb0 ); DCL2(jb1t, 1,Dct1 ,Dcb1 );
                DCL2(jb1t, 2,Dct2 ,Dcb2 ); DCL2(jb1t, 3,Dct3 ,Dcb3 );
                DCL2(jb1t, 4,Dct4 ,Dcb4 ); DCL2(jb1t, 5,Dct5 ,Dcb5 );
                DCL2(jb1t, 6,Dct6 ,Dcb6 ); DCL2(jb1t, 7,Dct7 ,Dcb7 );
                DCL2(jb1t, 8,Dct8 ,Dcb8 ); DCL2(jb1t, 9,Dct9 ,Dcb9 );
                DCL2(jb1t,10,Dct10,Dcb10); DCL2(jb1t,11,Dct11,Dcb11);
                DCL2(jb1t,12,Dct12,Dcb12); DCL2(jb1t,13,Dct13,Dcb13);
                DCL2(jb1t,14,Dct14,Dcb14); DCL2(jb1t,15,Dct15,Dcb15);
            } else {
                rhb14_last = rhb14;          // diag 2046, row 1023, col 1023
            }
        }

        // bottom-row store (lane 63's bottom half = row gbase+127)
        if (l == 63) {
            float4* dst = (float4*)&s_row[w_][u << 4];
            dst[0] = make_float4(rhb0,  rhb1,  rhb2,  rhb3);
            dst[1] = make_float4(rhb4,  rhb5,  rhb6,  rhb7);
            dst[2] = make_float4(rhb8,  rhb9,  rhb10, rhb11);
            dst[3] = make_float4(rhb12, rhb13, rhb14, rhb15);
        }

        // ---- mark window complete (LOCAL index) ----
        if (w_ < 3 && l == 0) {
            __hip_atomic_store(&s_prog[w_], u, __ATOMIC_RELEASE,
                               __HIP_MEMORY_SCOPE_WORKGROUP);
        }
        // ---- publisher: h==0, w_==3 (row 511) ----
        if (h == 0 && w_ == 3) {
            if (l < 16) {
                const int kk = k0 + l;                 // abs diag
                const unsigned long long ev =
                    ((unsigned long long)(unsigned)kk << 32) |
                    (unsigned long long)__float_as_uint(s_row[3][(u << 4) + l]);
                __hip_atomic_store(pub + (kk - KB), ev,
                                   __ATOMIC_RELAXED, __HIP_MEMORY_SCOPE_AGENT);
            }
        }
        // ---- cross-block consumer: prefetch next window ----
        if (h == 1 && w_ == 0 && u < 71) {
            const int kk1n = k0 + 15 + l;
            pe1 = __hip_atomic_load(con + min(kk1n - KB, RING - 1),
                                    __ATOMIC_RELAXED, __HIP_MEMORY_SCOPE_AGENT);
            ppf = 1;
        }
        // ---- intra-block consumer: prefetch next window if ready ----
        if (w_ != 0 && u < 71) {
            const int neednx = (u + 9 < 71) ? (u + 9) : 71;
            const int pv = __hip_atomic_load(&s_prog[w_ - 1], __ATOMIC_ACQUIRE,
                                             __HIP_MEMORY_SCOPE_WORKGROUP);
            if (pv >= neednx) {
                hpf1 = s_row[w_ - 1][min(((u + 1) << 4) + 127 + l, RING - 1)];
                hpff = 1;
            }
        }
    }
    if (h == 1 && tid == 255) ws[256 + b] = rhb14_last;   // r_{2T-2}(T-1)
#undef CHAIN2
#undef LOADH
#undef DM2
#undef DCL2
}

__global__ __launch_bounds__(256) void finalize2_kernel(
    const float* __restrict__ ws, float* __restrict__ out)
{
    __shared__ float sm[4], ss[4];
    const int tid = threadIdx.x, l = tid & 63, w = tid >> 6;
    float m  = (tid < 128) ? ws[tid] : 0.f;
    float sd = (tid < 64) ? ws[256 + tid] : 0.f;
    #pragma unroll
    for (int off = 32; off > 0; off >>= 1) {
        m  += __shfl_down(m,  off, 64);
        sd += __shfl_down(sd, off, 64);
    }
    if (l == 0) { sm[w] = m; ss[w] = sd; }
    __syncthreads();
    if (tid == 0) {
        float M = sm[0] + sm[1] + sm[2] + sm[3];
        float S = ss[0] + ss[1] + ss[2] + ss[3];
        out[0] = ALPHA_ * (M / 524288.0f) + (1.0f - ALPHA_) * (S / 64.0f);
    }
}

extern "C" void kernel_launch(void* const* d_in, const int* in_sizes, int n_in,
                              void* d_out, int out_size, void* d_ws, size_t ws_size,
                              hipStream_t stream) {
    const float* pred   = (const float*)d_in[0];
    const float* target = (const float*)d_in[1];
    float* ws  = (float*)d_ws;
    float* out = (float*)d_out;

    sdtw_band_kernel<<<128, 256, 0, stream>>>(pred, target, ws);
    finalize2_kernel<<<1, 256, 0, stream>>>(ws, out);
}

// Round 15
// 312.037 us; speedup vs baseline: 1.4174x; 1.4174x over previous
//
#include <hip/hip_runtime.h>

// CombinedLoss: 0.7*MSE + 0.3*mean_b softDTW_gamma.  B=64, T=1024, C=8, fp32.
// R22 (= R21 resubmit; round-14 bench died at container acquire -- third
// infra failure, rounds 5/10 both passed on verbatim resubmit; full K=32
// index-algebra audit clean).
// R21 = R19 with 32-diag windows (K=32).  Accounting: total = 2048*c +
// slots*F; R19 = 128 slots x ~5k cy with c~250cy/diag, F~900cy/window.
// K=32 halves window count AND halves the inter-wave lag (4->2 windows):
// slots 128 -> 64, saving ~64F ~= 10%.  All R19 machinery preserved under
// index scaling: amin=2g, halo idx 32u+63+l, publish l<32, hot u in [2,30],
// capture rh30@u=33; ring tags/sizes unchanged.  dg=up_prev carry (exact),
// 3-buffer D-load rotation, 48B-stride padded columns, 256 blocks x 256
// thr, 1 wave/SIMD, free-running waves, LDS progress flags intra-block,
// self-validating 8B atomics cross-block.
// ws: [0,256) mse | [256,320) sdtw | u64 rings @ float-offset 320 (~1.6 MB).

constexpr int TT = 1024;
constexpr float ALPHA_ = 0.7f;
constexpr float FINF = 1000000000.0f;
constexpr int RING = 1088;

__device__ __forceinline__ float shflup1(float old0, float v) {
    return __int_as_float(__builtin_amdgcn_update_dpp(
        __float_as_int(old0), __float_as_int(v), 0x138, 0xf, 0xf, false));
}
__device__ __forceinline__ float rotdn1(float v) {
    return __int_as_float(__builtin_amdgcn_update_dpp(
        0, __float_as_int(v), 0x130, 0xf, 0xf, false));
}

__global__ __launch_bounds__(256) void sdtw_band_kernel(
    const float* __restrict__ pred, const float* __restrict__ target,
    float* __restrict__ ws)
{
    // col j: A-half at 3j, B-half at 3j+1, y2 at 3j+2.x (48B stride)
    __shared__ float4 s_c4[TT * 3];
    __shared__ float  s_row[4][1088];    // per-wave bottom row, local diag idx
    __shared__ float  s_red[4];
    __shared__ int    s_prog[4];         // last completed ABS window per wave

    const int blk = blockIdx.x;
    const int b   = blk & 63;                  // batch (q*64+b: same-XCD bands)
    const int q   = blk >> 6;                  // band
    const int tid = threadIdx.x;
    const int l   = tid & 63;
    const int w_  = __builtin_amdgcn_readfirstlane(tid >> 6);
    const int g   = (q << 2) + w_;             // global wave 0..15
    const int gbase = g << 6;
    const int row   = gbase + l;

    if (tid < 4) s_prog[tid] = -1;

    const float* pr = pred   + ((size_t)b * TT + row) * 8;
    const float* tr = target + ((size_t)b * TT + row) * 8;
    const float4 pa = ((const float4*)pr)[0];
    const float4 pb = ((const float4*)pr)[1];
    const float4 ma = ((const float4*)tr)[0];
    const float4 mb = ((const float4*)tr)[1];

    float x2 = 0.f, msep = 0.f;
    {
        const float pp[8] = {pa.x,pa.y,pa.z,pa.w,pb.x,pb.y,pb.z,pb.w};
        const float tt[8] = {ma.x,ma.y,ma.z,ma.w,mb.x,mb.y,mb.z,mb.w};
        #pragma unroll
        for (int c = 0; c < 8; ++c) {
            x2 = fmaf(pp[c], pp[c], x2);
            float d = pp[c] - tt[c];
            msep = fmaf(d, d, msep);
        }
    }
    // stage all 1024 columns (4 per thread), padded layout
    const float* tg = target + (size_t)b * TT * 8;
    #pragma unroll
    for (int c0 = 0; c0 < 4; ++c0) {
        const int col = tid + (c0 << 8);
        const float4 u0 = ((const float4*)(tg + (size_t)col * 8))[0];
        const float4 u1 = ((const float4*)(tg + (size_t)col * 8))[1];
        const float y2 = u0.x*u0.x + u0.y*u0.y + u0.z*u0.z + u0.w*u0.w
                       + u1.x*u1.x + u1.y*u1.y + u1.z*u1.z + u1.w*u1.w;
        s_c4[3*col]   = make_float4(-2.f*u0.x, -2.f*u0.y, -2.f*u0.z, -2.f*u0.w);
        s_c4[3*col+1] = make_float4(-2.f*u1.x, -2.f*u1.y, -2.f*u1.z, -2.f*u1.w);
        s_c4[3*col+2] = make_float4(y2, 0.f, 0.f, 0.f);
    }
    #pragma unroll
    for (int off = 32; off > 0; off >>= 1) msep += __shfl_down(msep, off, 64);
    if (l == 0) s_red[w_] = msep;
    __syncthreads();                      // the ONLY block-wide barrier
    if (tid == 0) ws[blk] = s_red[0] + s_red[1] + s_red[2] + s_red[3];

    unsigned long long* rings = (unsigned long long*)(ws + 320);
    unsigned long long* pub = rings + (size_t)(q * 64 + b) * RING;       // w_==3,q<3
    unsigned long long* con = rings + (size_t)((q - 1) * 64 + b) * RING; // w_==0,q>0
    const int kb_pub   = 256 * q + 192;
    const int kb_con   = 256 * q - 64;
    const int kmax_con = kb_con + 1086;

    const float c1 = 7.213475204444817f;     // log2(e)/gamma
    const float c2 = 0.13862943611198906f;   // gamma*ln(2)
    const int amin = g << 1;                 // first abs 32-window = 2g
    const int prodmax = amin + 31;           // producer's last abs window

    float r1 = FINF;
    float dgp;                               // dg(d) = up(d-1), carried
    unsigned long long pe1 = 0;
    int ppf = 0;
    float hpf1 = 0.f;
    int hpff = 0;
    float hv;

    // ---- pre-loop: stage hvd (diag 64g-2) once, seed dgp ----
    {
        float hvd0;
        if (w_ == 0) {
            if (q == 0) {
                hvd0 = (l == 0) ? 0.0f : FINF;
            } else {
                const int kk2 = (g << 6) - 2 + l;
                const int id2 = min(kk2 - kb_con, RING - 1);
                const bool n2 = (l < 16) && (kk2 <= kmax_con);
                unsigned long long e2;
                do {
                    e2 = __hip_atomic_load(con + id2, __ATOMIC_RELAXED,
                                           __HIP_MEMORY_SCOPE_AGENT);
                } while (!__all((!n2) | ((int)(e2 >> 32) == kk2)));
                hvd0 = n2 ? __uint_as_float((unsigned)e2) : FINF;
            }
        } else {
            int pv;
            do {
                pv = __hip_atomic_load(&s_prog[w_ - 1], __ATOMIC_ACQUIRE,
                                       __HIP_MEMORY_SCOPE_WORKGROUP);
            } while (pv < amin);
            hvd0 = s_row[w_ - 1][min(62 + l, 1087)];
        }
        dgp = shflup1(hvd0, FINF);           // lane0 <- hvd0[0], others FINF
    }

// ---- hot step: chain with in-chain D load (step i) + D math (step i-2) ----
#define STEPF(i, BA,BB,BY, CA,CB,CY, DCI, DC2, RH) do {                     \
        const float up_ = shflup1(hv, r1);                                  \
        hv = rotdn1(hv);                                                    \
        const int j_ = jb1 + (i);                                           \
        BA = s_c4[3*j_]; BB = s_c4[3*j_+1]; BY = s_c4[3*j_+2].x;            \
        float m_, M_;                                                       \
        asm("v_min3_f32 %0, %1, %2, %3"                                     \
            : "=v"(m_) : "v"(up_), "v"(r1), "v"(dgp));                      \
        asm("v_max3_f32 %0, %1, %2, %3"                                     \
            : "=v"(M_) : "v"(up_), "v"(r1), "v"(dgp));                      \
        const float md_ = __builtin_amdgcn_fmed3f(up_, r1, dgp);            \
        dgp = up_;                                                          \
        const float mc_ = m_ * c1;                                          \
        const float ea_ = __builtin_amdgcn_exp2f(fmaf(md_, -c1, mc_));      \
        const float eb_ = __builtin_amdgcn_exp2f(fmaf(M_,  -c1, mc_));      \
        {   float ac_ = x2 + CY, ac2_ = 0.f;                                \
            ac_  = fmaf(pa.x, CA.x, ac_ );  ac2_ = fmaf(pa.y, CA.y, ac2_);  \
            ac_  = fmaf(pa.z, CA.z, ac_ );  ac2_ = fmaf(pa.w, CA.w, ac2_);  \
            ac_  = fmaf(pb.x, CB.x, ac_ );  ac2_ = fmaf(pb.y, CB.y, ac2_);  \
            ac_  = fmaf(pb.z, CB.z, ac_ );  ac2_ = fmaf(pb.w, CB.w, ac2_);  \
            DC2 = ac_ + ac2_; }                                             \
        const float lg_ = __builtin_amdgcn_logf(1.0f + (ea_ + eb_));        \
        const float rn_ = (DCI) + fmaf(-c2, lg_, m_);                       \
        r1 = rn_; RH = rn_;                                                 \
    } while (0)

// hot step without the i-2 math (steps 0,1)
#define STEPF0(i, BA,BB,BY, DCI, RH) do {                                   \
        const float up_ = shflup1(hv, r1);                                  \
        hv = rotdn1(hv);                                                    \
        const int j_ = jb1 + (i);                                           \
        BA = s_c4[3*j_]; BB = s_c4[3*j_+1]; BY = s_c4[3*j_+2].x;            \
        float m_, M_;                                                       \
        asm("v_min3_f32 %0, %1, %2, %3"                                     \
            : "=v"(m_) : "v"(up_), "v"(r1), "v"(dgp));                      \
        asm("v_max3_f32 %0, %1, %2, %3"                                     \
            : "=v"(M_) : "v"(up_), "v"(r1), "v"(dgp));                      \
        const float md_ = __builtin_amdgcn_fmed3f(up_, r1, dgp);            \
        dgp = up_;                                                          \
        const float mc_ = m_ * c1;                                          \
        const float ea_ = __builtin_amdgcn_exp2f(fmaf(md_, -c1, mc_));      \
        const float eb_ = __builtin_amdgcn_exp2f(fmaf(M_,  -c1, mc_));      \
        const float lg_ = __builtin_amdgcn_logf(1.0f + (ea_ + eb_));        \
        const float rn_ = (DCI) + fmaf(-c2, lg_, m_);                       \
        r1 = rn_; RH = rn_;                                                 \
    } while (0)

// tail math for the last two loads of a hot window
#define DMATHT(CA,CB,CY, DC2) do {                                          \
        float ac_ = x2 + CY, ac2_ = 0.f;                                    \
        ac_  = fmaf(pa.x, CA.x, ac_ );  ac2_ = fmaf(pa.y, CA.y, ac2_);      \
        ac_  = fmaf(pa.z, CA.z, ac_ );  ac2_ = fmaf(pa.w, CA.w, ac2_);      \
        ac_  = fmaf(pb.x, CB.x, ac_ );  ac2_ = fmaf(pb.y, CB.y, ac2_);      \
        ac_  = fmaf(pb.z, CB.z, ac_ );  ac2_ = fmaf(pb.w, CB.w, ac2_);      \
        DC2 = ac_ + ac2_;                                                   \
    } while (0)

// edge step: masked recurrence
#define STEPE(i, DCI, RH) do {                                              \
        const float up_ = shflup1(hv, r1);                                  \
        hv = rotdn1(hv);                                                    \
        float m_, M_;                                                       \
        asm("v_min3_f32 %0, %1, %2, %3"                                     \
            : "=v"(m_) : "v"(up_), "v"(r1), "v"(dgp));                      \
        asm("v_max3_f32 %0, %1, %2, %3"                                     \
            : "=v"(M_) : "v"(up_), "v"(r1), "v"(dgp));                      \
        const float md_ = __builtin_amdgcn_fmed3f(up_, r1, dgp);            \
        dgp = up_;                                                          \
        const float mc_ = m_ * c1;                                          \
        const float ea_ = __builtin_amdgcn_exp2f(fmaf(md_, -c1, mc_));      \
        const float eb_ = __builtin_amdgcn_exp2f(fmaf(M_,  -c1, mc_));      \
        const float lg_ = __builtin_amdgcn_logf(1.0f + (ea_ + eb_));        \
        float rn_ = (DCI) + fmaf(-c2, lg_, m_);                             \
        rn_ = ((unsigned)(jb0 + (i)) < (unsigned)TT) ? rn_ : FINF;          \
        r1 = rn_; RH = rn_;                                                 \
    } while (0)

// clamped D (edge windows / prologue)
#define DCLAMP(JB, i, DC) do {                                              \
        int jc_ = (JB) + (i);                                               \
        jc_ = jc_ < 0 ? 0 : (jc_ > (TT-1) ? (TT-1) : jc_);                  \
        const float4 va_ = s_c4[3*jc_];                                     \
        const float4 vb_ = s_c4[3*jc_+1];                                   \
        const float  yv_ = s_c4[3*jc_+2].x;                                 \
        float ac_ = x2 + yv_, ac2_ = 0.f;                                   \
        ac_  = fmaf(pa.x, va_.x, ac_ );  ac2_ = fmaf(pa.y, va_.y, ac2_);    \
        ac_  = fmaf(pa.z, va_.z, ac_ );  ac2_ = fmaf(pa.w, va_.w, ac2_);    \
        ac_  = fmaf(pb.x, vb_.x, ac_ );  ac2_ = fmaf(pb.y, vb_.y, ac2_);    \
        ac_  = fmaf(pb.z, vb_.z, ac_ );  ac2_ = fmaf(pb.w, vb_.w, ac2_);    \
        DC = ac_ + ac2_;                                                    \
    } while (0)

    // D for window 0 (prologue, clamped)
    float Dc0,Dc1,Dc2,Dc3,Dc4,Dc5,Dc6,Dc7;
    float Dc8,Dc9,Dc10,Dc11,Dc12,Dc13,Dc14,Dc15;
    float Dc16,Dc17,Dc18,Dc19,Dc20,Dc21,Dc22,Dc23;
    float Dc24,Dc25,Dc26,Dc27,Dc28,Dc29,Dc30,Dc31;
    {
        const int jb = -l;
        DCLAMP(jb, 0,Dc0 ); DCLAMP(jb, 1,Dc1 ); DCLAMP(jb, 2,Dc2 );
        DCLAMP(jb, 3,Dc3 ); DCLAMP(jb, 4,Dc4 ); DCLAMP(jb, 5,Dc5 );
        DCLAMP(jb, 6,Dc6 ); DCLAMP(jb, 7,Dc7 ); DCLAMP(jb, 8,Dc8 );
        DCLAMP(jb, 9,Dc9 ); DCLAMP(jb,10,Dc10); DCLAMP(jb,11,Dc11);
        DCLAMP(jb,12,Dc12); DCLAMP(jb,13,Dc13); DCLAMP(jb,14,Dc14);
        DCLAMP(jb,15,Dc15); DCLAMP(jb,16,Dc16); DCLAMP(jb,17,Dc17);
        DCLAMP(jb,18,Dc18); DCLAMP(jb,19,Dc19); DCLAMP(jb,20,Dc20);
        DCLAMP(jb,21,Dc21); DCLAMP(jb,22,Dc22); DCLAMP(jb,23,Dc23);
        DCLAMP(jb,24,Dc24); DCLAMP(jb,25,Dc25); DCLAMP(jb,26,Dc26);
        DCLAMP(jb,27,Dc27); DCLAMP(jb,28,Dc28); DCLAMP(jb,29,Dc29);
        DCLAMP(jb,30,Dc30); DCLAMP(jb,31,Dc31);
    }
    float rh30_last = FINF;
    float4 vA0, vB0, vA1, vB1, vA2, vB2;
    float  yv0, yv1, yv2;

    for (int u = 0; u <= 33; ++u) {
        const int a  = amin + u;
        const int k0 = a << 5;
        const int jb0 = (u << 5) - l;        // col index of diag k0 at this lane
        const int jb1 = jb0 + 32;            // same for window u+1

        // ---- stage halo hv (diag k0-1) ----
        if (w_ == 0) {
            if (q == 0) {
                hv = FINF;
            } else {
                const int kk1 = k0 - 1 + l;
                const int id1 = min(kk1 - kb_con, RING - 1);
                const bool n1 = (l < 32) && (kk1 <= kmax_con);
                unsigned long long e1;
                if (ppf) { e1 = pe1; ppf = 0; }
                else {
                    e1 = __hip_atomic_load(con + id1, __ATOMIC_RELAXED,
                                           __HIP_MEMORY_SCOPE_AGENT);
                }
                while (!__all((!n1) | ((int)(e1 >> 32) == kk1))) {
                    e1 = __hip_atomic_load(con + id1, __ATOMIC_RELAXED,
                                           __HIP_MEMORY_SCOPE_AGENT);
                }
                hv = n1 ? __uint_as_float((unsigned)e1) : FINF;
            }
        } else {
            if (hpff) { hv = hpf1; hpff = 0; }
            else {
                const int need = (a < prodmax) ? a : prodmax;
                int pv;
                do {
                    pv = __hip_atomic_load(&s_prog[w_ - 1], __ATOMIC_ACQUIRE,
                                           __HIP_MEMORY_SCOPE_WORKGROUP);
                } while (pv < need);
                hv = s_row[w_ - 1][min((u << 5) + 63 + l, 1087)];
            }
        }

        float rh0,rh1,rh2,rh3,rh4,rh5,rh6,rh7;
        float rh8,rh9,rh10,rh11,rh12,rh13,rh14,rh15;
        float rh16,rh17,rh18,rh19,rh20,rh21,rh22,rh23;
        float rh24,rh25,rh26,rh27,rh28,rh29,rh30,rh31;

        if (u >= 2 && u <= 30) {
            STEPF0( 0, vA0,vB0,yv0,               Dc0 , rh0 );
            STEPF0( 1, vA1,vB1,yv1,               Dc1 , rh1 );
            STEPF ( 2, vA2,vB2,yv2, vA0,vB0,yv0,  Dc2 , Dc0 , rh2 );
            STEPF ( 3, vA0,vB0,yv0, vA1,vB1,yv1,  Dc3 , Dc1 , rh3 );
            STEPF ( 4, vA1,vB1,yv1, vA2,vB2,yv2,  Dc4 , Dc2 , rh4 );
            STEPF ( 5, vA2,vB2,yv2, vA0,vB0,yv0,  Dc5 , Dc3 , rh5 );
            STEPF ( 6, vA0,vB0,yv0, vA1,vB1,yv1,  Dc6 , Dc4 , rh6 );
            STEPF ( 7, vA1,vB1,yv1, vA2,vB2,yv2,  Dc7 , Dc5 , rh7 );
            STEPF ( 8, vA2,vB2,yv2, vA0,vB0,yv0,  Dc8 , Dc6 , rh8 );
            STEPF ( 9, vA0,vB0,yv0, vA1,vB1,yv1,  Dc9 , Dc7 , rh9 );
            STEPF (10, vA1,vB1,yv1, vA2,vB2,yv2,  Dc10, Dc8 , rh10);
            STEPF (11, vA2,vB2,yv2, vA0,vB0,yv0,  Dc11, Dc9 , rh11);
            STEPF (12, vA0,vB0,yv0, vA1,vB1,yv1,  Dc12, Dc10, rh12);
            STEPF (13, vA1,vB1,yv1, vA2,vB2,yv2,  Dc13, Dc11, rh13);
            STEPF (14, vA2,vB2,yv2, vA0,vB0,yv0,  Dc14, Dc12, rh14);
            STEPF (15, vA0,vB0,yv0, vA1,vB1,yv1,  Dc15, Dc13, rh15);
            STEPF (16, vA1,vB1,yv1, vA2,vB2,yv2,  Dc16, Dc14, rh16);
            STEPF (17, vA2,vB2,yv2, vA0,vB0,yv0,  Dc17, Dc15, rh17);
            STEPF (18, vA0,vB0,yv0, vA1,vB1,yv1,  Dc18, Dc16, rh18);
            STEPF (19, vA1,vB1,yv1, vA2,vB2,yv2,  Dc19, Dc17, rh19);
            STEPF (20, vA2,vB2,yv2, vA0,vB0,yv0,  Dc20, Dc18, rh20);
            STEPF (21, vA0,vB0,yv0, vA1,vB1,yv1,  Dc21, Dc19, rh21);
            STEPF (22, vA1,vB1,yv1, vA2,vB2,yv2,  Dc22, Dc20, rh22);
            STEPF (23, vA2,vB2,yv2, vA0,vB0,yv0,  Dc23, Dc21, rh23);
            STEPF (24, vA0,vB0,yv0, vA1,vB1,yv1,  Dc24, Dc22, rh24);
            STEPF (25, vA1,vB1,yv1, vA2,vB2,yv2,  Dc25, Dc23, rh25);
            STEPF (26, vA2,vB2,yv2, vA0,vB0,yv0,  Dc26, Dc24, rh26);
            STEPF (27, vA0,vB0,yv0, vA1,vB1,yv1,  Dc27, Dc25, rh27);
            STEPF (28, vA1,vB1,yv1, vA2,vB2,yv2,  Dc28, Dc26, rh28);
            STEPF (29, vA2,vB2,yv2, vA0,vB0,yv0,  Dc29, Dc27, rh29);
            STEPF (30, vA0,vB0,yv0, vA1,vB1,yv1,  Dc30, Dc28, rh30);
            STEPF (31, vA1,vB1,yv1, vA2,vB2,yv2,  Dc31, Dc29, rh31);
            DMATHT(vA0,vB0,yv0, Dc30);
            DMATHT(vA1,vB1,yv1, Dc31);
        } else {
            STEPE( 0,Dc0 ,rh0 ); STEPE( 1,Dc1 ,rh1 );
            STEPE( 2,Dc2 ,rh2 ); STEPE( 3,Dc3 ,rh3 );
            STEPE( 4,Dc4 ,rh4 ); STEPE( 5,Dc5 ,rh5 );
            STEPE( 6,Dc6 ,rh6 ); STEPE( 7,Dc7 ,rh7 );
            STEPE( 8,Dc8 ,rh8 ); STEPE( 9,Dc9 ,rh9 );
            STEPE(10,Dc10,rh10); STEPE(11,Dc11,rh11);
            STEPE(12,Dc12,rh12); STEPE(13,Dc13,rh13);
            STEPE(14,Dc14,rh14); STEPE(15,Dc15,rh15);
            STEPE(16,Dc16,rh16); STEPE(17,Dc17,rh17);
            STEPE(18,Dc18,rh18); STEPE(19,Dc19,rh19);
            STEPE(20,Dc20,rh20); STEPE(21,Dc21,rh21);
            STEPE(22,Dc22,rh22); STEPE(23,Dc23,rh23);
            STEPE(24,Dc24,rh24); STEPE(25,Dc25,rh25);
            STEPE(26,Dc26,rh26); STEPE(27,Dc27,rh27);
            STEPE(28,Dc28,rh28); STEPE(29,Dc29,rh29);
            STEPE(30,Dc30,rh30); STEPE(31,Dc31,rh31);
            if (u < 33) {
                DCLAMP(jb1, 0,Dc0 ); DCLAMP(jb1, 1,Dc1 ); DCLAMP(jb1, 2,Dc2 );
                DCLAMP(jb1, 3,Dc3 ); DCLAMP(jb1, 4,Dc4 ); DCLAMP(jb1, 5,Dc5 );
                DCLAMP(jb1, 6,Dc6 ); DCLAMP(jb1, 7,Dc7 ); DCLAMP(jb1, 8,Dc8 );
                DCLAMP(jb1, 9,Dc9 ); DCLAMP(jb1,10,Dc10); DCLAMP(jb1,11,Dc11);
                DCLAMP(jb1,12,Dc12); DCLAMP(jb1,13,Dc13); DCLAMP(jb1,14,Dc14);
                DCLAMP(jb1,15,Dc15); DCLAMP(jb1,16,Dc16); DCLAMP(jb1,17,Dc17);
                DCLAMP(jb1,18,Dc18); DCLAMP(jb1,19,Dc19); DCLAMP(jb1,20,Dc20);
                DCLAMP(jb1,21,Dc21); DCLAMP(jb1,22,Dc22); DCLAMP(jb1,23,Dc23);
                DCLAMP(jb1,24,Dc24); DCLAMP(jb1,25,Dc25); DCLAMP(jb1,26,Dc26);
                DCLAMP(jb1,27,Dc27); DCLAMP(jb1,28,Dc28); DCLAMP(jb1,29,Dc29);
                DCLAMP(jb1,30,Dc30); DCLAMP(jb1,31,Dc31);
            } else {
                rh30_last = rh30;            // diag 2046, row 1023, col 1023
            }
        }

        // bottom-row store
        if (l == 63) {
            float4* dst = (float4*)&s_row[w_][u << 5];
            dst[0] = make_float4(rh0,  rh1,  rh2,  rh3);
            dst[1] = make_float4(rh4,  rh5,  rh6,  rh7);
            dst[2] = make_float4(rh8,  rh9,  rh10, rh11);
            dst[3] = make_float4(rh12, rh13, rh14, rh15);
            dst[4] = make_float4(rh16, rh17, rh18, rh19);
            dst[5] = make_float4(rh20, rh21, rh22, rh23);
            dst[6] = make_float4(rh24, rh25, rh26, rh27);
            dst[7] = make_float4(rh28, rh29, rh30, rh31);
        }

        // ---- mark window complete for intra-block consumer ----
        if (w_ < 3 && l == 0) {
            __hip_atomic_store(&s_prog[w_], a, __ATOMIC_RELEASE,
                               __HIP_MEMORY_SCOPE_WORKGROUP);
        }
        // ---- producer: publish window as self-validating u64 entries ----
        if (w_ == 3 && q < 3) {
            if (l < 32) {
                const int kk = k0 + l;
                const unsigned long long ev =
                    ((unsigned long long)(unsigned)kk << 32) |
                    (unsigned long long)__float_as_uint(s_row[3][(u << 5) + l]);
                __hip_atomic_store(pub + (kk - kb_pub), ev,
                                   __ATOMIC_RELAXED, __HIP_MEMORY_SCOPE_AGENT);
            }
        }
        // ---- cross-block consumer: prefetch next window's hv entries ----
        if (w_ == 0 && q > 0 && u < 33) {
            const int kk1 = k0 + 31 + l;
            pe1 = __hip_atomic_load(con + min(kk1 - kb_con, RING - 1),
                                    __ATOMIC_RELAXED, __HIP_MEMORY_SCOPE_AGENT);
            ppf = 1;
        }
        // ---- intra-block consumer: prefetch next window's hv if ready ----
        if (w_ != 0 && u < 33) {
            const int neednx = ((a + 1) < prodmax) ? (a + 1) : prodmax;
            const int pv = __hip_atomic_load(&s_prog[w_ - 1], __ATOMIC_ACQUIRE,
                                             __HIP_MEMORY_SCOPE_WORKGROUP);
            if (pv >= neednx) {
                hpf1 = s_row[w_ - 1][min(((u + 1) << 5) + 63 + l, 1087)];
                hpff = 1;
            }
        }
    }
    if (q == 3 && tid == 255) ws[256 + b] = rh30_last;   // r_{2T-2}(T-1)
#undef STEPF
#undef STEPF0
#undef DMATHT
#undef STEPE
#undef DCLAMP
}

__global__ __launch_bounds__(256) void finalize2_kernel(
    const float* __restrict__ ws, float* __restrict__ out)
{
    __shared__ float sm[4], ss[4];
    const int tid = threadIdx.x, l = tid & 63, w = tid >> 6;
    float m  = ws[tid];
    float sd = (tid < 64) ? ws[256 + tid] : 0.f;
    #pragma unroll
    for (int off = 32; off > 0; off >>= 1) {
        m  += __shfl_down(m,  off, 64);
        sd += __shfl_down(sd, off, 64);
    }
    if (l == 0) { sm[w] = m; ss[w] = sd; }
    __syncthreads();
    if (tid == 0) {
        float M = sm[0] + sm[1] + sm[2] + sm[3];
        float S = ss[0] + ss[1] + ss[2] + ss[3];
        out[0] = ALPHA_ * (M / 524288.0f) + (1.0f - ALPHA_) * (S / 64.0f);
    }
}

extern "C" void kernel_launch(void* const* d_in, const int* in_sizes, int n_in,
                              void* d_out, int out_size, void* d_ws, size_t ws_size,
                              hipStream_t stream) {
    const float* pred   = (const float*)d_in[0];
    const float* target = (const float*)d_in[1];
    float* ws  = (float*)d_ws;
    float* out = (float*)d_out;

    sdtw_band_kernel<<<256, 256, 0, stream>>>(pred, target, ws);
    finalize2_kernel<<<1, 256, 0, stream>>>(ws, out);
}